// Round 2
// baseline (126.896 us; speedup 1.0000x reference)
//
#include <hip/hip_runtime.h>
#include <hip/hip_bf16.h>

#define E 8192
#define C 128
#define LISTCAP 256

typedef unsigned int u32;
typedef unsigned long long u64;

// true iff either 16-bit half of v is zero (exact)
__device__ __forceinline__ bool hz(u32 v) {
    return ((v - 0x00010001u) & ~v & 0x80008000u) != 0u;
}

// Kernel 1: h = x@W (f32), a_src = h@att_src, a_dst = h@att_dst, pack (s<<16|d).
// 256 threads = 4 waves; each wave computes 4 rows. grid = E/16 = 512 blocks.
__global__ __launch_bounds__(256) void gat_prep(
    const float* __restrict__ x, const float* __restrict__ W,
    const float* __restrict__ att_s, const float* __restrict__ att_d,
    const int* __restrict__ ei,
    float* __restrict__ h, float* __restrict__ asrc, float* __restrict__ adst,
    int* __restrict__ packed)
{
    const int tid = threadIdx.x, lane = tid & 63, wv = tid >> 6;
    const int g = blockIdx.x * 256 + tid;
    if (g < E) packed[g] = ((ei[g] & 0xffff) << 16) | (ei[E + g] & 0xffff);

    const int row0 = blockIdx.x * 16 + wv * 4;
    __shared__ float xs[4][4][C];
    #pragma unroll
    for (int r = 0; r < 4; ++r) {
        *reinterpret_cast<float2*>(&xs[wv][r][2 * lane]) =
            *reinterpret_cast<const float2*>(&x[(size_t)(row0 + r) * C + 2 * lane]);
    }
    __syncthreads();

    float acc[4][2] = {};
    for (int k4 = 0; k4 < C; k4 += 4) {
        float4 xk[4];
        #pragma unroll
        for (int r = 0; r < 4; ++r)
            xk[r] = *reinterpret_cast<const float4*>(&xs[wv][r][k4]);
        #pragma unroll
        for (int kk = 0; kk < 4; ++kk) {
            const float2 wv2 = *reinterpret_cast<const float2*>(&W[(size_t)(k4 + kk) * C + 2 * lane]);
            #pragma unroll
            for (int r = 0; r < 4; ++r) {
                const float xv = reinterpret_cast<const float*>(&xk[r])[kk];
                acc[r][0] = fmaf(xv, wv2.x, acc[r][0]);
                acc[r][1] = fmaf(xv, wv2.y, acc[r][1]);
            }
        }
    }

    const float2 asv = *reinterpret_cast<const float2*>(&att_s[2 * lane]);
    const float2 adv = *reinterpret_cast<const float2*>(&att_d[2 * lane]);
    #pragma unroll
    for (int r = 0; r < 4; ++r) {
        const int row = row0 + r;
        *reinterpret_cast<float2*>(&h[(size_t)row * C + 2 * lane]) =
            make_float2(acc[r][0], acc[r][1]);
        float ps = fmaf(acc[r][0], asv.x, acc[r][1] * asv.y);
        float pd = fmaf(acc[r][0], adv.x, acc[r][1] * adv.y);
        #pragma unroll
        for (int off = 32; off > 0; off >>= 1) {
            ps += __shfl_xor(ps, off);
            pd += __shfl_xor(pd, off);
        }
        if (lane == 0) { asrc[row] = ps; adst[row] = pd; }
    }
}

// Kernel 2: one wave per target edge. Scan all 8192 packed (s,d) (LDS-staged,
// 4 candidates/lane/round), collect valid (j, leakyrelu(score)) into per-wave
// LDS list via ballot-prefix (deterministic), then softmax + h-row gather.
__global__ __launch_bounds__(256) void gat_aggr(
    const int* __restrict__ packed,
    const float* __restrict__ h,
    const float* __restrict__ asrc, const float* __restrict__ adst,
    const float* __restrict__ bias,
    float* __restrict__ out)
{
    __shared__ int sp[E];                 // 32 KB packed (s,d)
    __shared__ float2 lst[4][LISTCAP];    // 8 KB per-wave candidate lists
    const int tid = threadIdx.x, lane = tid & 63, wv = tid >> 6;

    for (int t = tid; t < E / 4; t += 256)
        reinterpret_cast<int4*>(sp)[t] = reinterpret_cast<const int4*>(packed)[t];
    __syncthreads();

    const int i = blockIdx.x * 4 + wv;
    const u32 pi = (u32)sp[i];
    const u32 si = pi >> 16, di = pi & 0xffffu;
    const u32 pss = (si << 16) | si, pdd = (di << 16) | di;
    const float adi = adst[i];

    // Pass 1: adjacency scan + list build.
    int base = 0;
    for (int r = 0; r < E / 256; ++r) {
        const int4 cq = *reinterpret_cast<const int4*>(&sp[(r << 8) + (lane << 2)]);
        #pragma unroll
        for (int q = 0; q < 4; ++q) {
            const u32 pj = (u32)(q == 0 ? cq.x : q == 1 ? cq.y : q == 2 ? cq.z : cq.w);
            const bool v = hz(pj ^ pss) || hz(pj ^ pdd);
            const u64 mask = __ballot(v);
            if (v) {
                const int j = (r << 8) + (lane << 2) + q;
                float sc = adi + asrc[j];
                sc = sc >= 0.f ? sc : 0.2f * sc;
                const int slot = base + (int)__popcll(mask & ((1ull << lane) - 1ull));
                if (slot < LISTCAP)
                    lst[wv][slot] = make_float2(__int_as_float(j), sc);
            }
            base += (int)__popcll(mask);
        }
    }
    __syncthreads();

    const int nc = base < LISTCAP ? base : LISTCAP;  // nc >= 1 (self always valid)

    // Row max (wave reduce).
    float m = -1e30f;
    for (int t = lane; t < nc; t += 64) m = fmaxf(m, lst[wv][t].y);
    #pragma unroll
    for (int off = 32; off > 0; off >>= 1) m = fmaxf(m, __shfl_xor(m, off));

    // Pass 2: softmax weights + weighted sum of h rows (lane owns 2 channels).
    float lsum = 0.f, a0 = 0.f, a1 = 0.f;
    for (int t = 0; t < nc; ++t) {
        const float2 e = lst[wv][t];
        const int j = __float_as_int(e.x);
        const float p = __expf(e.y - m);
        lsum += p;
        const float2 hv = *reinterpret_cast<const float2*>(&h[(size_t)j * C + 2 * lane]);
        a0 = fmaf(p, hv.x, a0);
        a1 = fmaf(p, hv.y, a1);
    }
    const float inv = 1.0f / lsum;
    const float2 bv = *reinterpret_cast<const float2*>(&bias[2 * lane]);
    *reinterpret_cast<float2*>(&out[(size_t)i * C + 2 * lane]) =
        make_float2(fmaf(a0, inv, bv.x), fmaf(a1, inv, bv.y));
}

extern "C" void kernel_launch(void* const* d_in, const int* in_sizes, int n_in,
                              void* d_out, int out_size, void* d_ws, size_t ws_size,
                              hipStream_t stream) {
    const float* x     = (const float*)d_in[0];
    const int*   ei    = (const int*)d_in[1];
    const float* W     = (const float*)d_in[2];
    const float* att_s = (const float*)d_in[3];
    const float* att_d = (const float*)d_in[4];
    const float* bias  = (const float*)d_in[5];

    float* h      = (float*)d_ws;            // E*C f32 = 4 MB
    float* asrc   = h + (size_t)E * C;       // 32 KB
    float* adst   = asrc + E;                // 32 KB
    int*   packed = (int*)(adst + E);        // 32 KB

    gat_prep<<<E / 16, 256, 0, stream>>>(x, W, att_s, att_d, ei, h, asrc, adst, packed);
    gat_aggr<<<E / 4, 256, 0, stream>>>(packed, h, asrc, adst, bias, (float*)d_out);
}

// Round 3
// 38.241 us; speedup vs baseline: 3.3183x; 3.3183x over previous
//
#include <hip/hip_runtime.h>

#define E 8192
#define NNODE 2048
#define C 128
#define CAPN 32   // max stored edges per node (Poisson(8) tail; P(deg>32) ~ 1e-13)

typedef unsigned int u32;
typedef unsigned long long u64;

// Kernel 1: h = x@W (f32), a_src/a_dst dots, packed endpoints, and inverted
// node->edge index via atomic slot placement (order canonicalized later).
// 256 threads = 4 waves; each wave computes 4 rows of h. grid = E/16 = 512.
__global__ __launch_bounds__(256) void gat_prep(
    const float* __restrict__ x, const float* __restrict__ W,
    const float* __restrict__ att_s, const float* __restrict__ att_d,
    const int* __restrict__ ei,
    float* __restrict__ h, float* __restrict__ asrc, float* __restrict__ adst,
    int* __restrict__ packed, int* __restrict__ cnt, int* __restrict__ nlist)
{
    const int tid = threadIdx.x, lane = tid & 63, wv = tid >> 6;
    const int g = blockIdx.x * 256 + tid;
    if (g < E) {  // block-uniform predicate (blocks 0..31)
        const int s = ei[g], d = ei[E + g];
        packed[g] = (s << 16) | d;
        int slot = atomicAdd(&cnt[s], 1);
        if (slot < CAPN) nlist[s * CAPN + slot] = g;
        if (d != s) {
            slot = atomicAdd(&cnt[d], 1);
            if (slot < CAPN) nlist[d * CAPN + slot] = g;
        }
    }

    const int row0 = blockIdx.x * 16 + wv * 4;
    __shared__ __align__(16) float xs[4][4][C];
    #pragma unroll
    for (int r = 0; r < 4; ++r)
        *reinterpret_cast<float2*>(&xs[wv][r][2 * lane]) =
            *reinterpret_cast<const float2*>(&x[(size_t)(row0 + r) * C + 2 * lane]);
    __syncthreads();

    float a00 = 0.f, a01 = 0.f, a10 = 0.f, a11 = 0.f;
    float a20 = 0.f, a21 = 0.f, a30 = 0.f, a31 = 0.f;
    const float4* xp0 = reinterpret_cast<const float4*>(xs[wv][0]);
    const float4* xp1 = reinterpret_cast<const float4*>(xs[wv][1]);
    const float4* xp2 = reinterpret_cast<const float4*>(xs[wv][2]);
    const float4* xp3 = reinterpret_cast<const float4*>(xs[wv][3]);
    const float* Wc = W + 2 * lane;

#define ROWFMA(V, A0, A1)                                    \
    A0 = fmaf(V.x, w0.x, A0); A1 = fmaf(V.x, w0.y, A1);      \
    A0 = fmaf(V.y, w1.x, A0); A1 = fmaf(V.y, w1.y, A1);      \
    A0 = fmaf(V.z, w2.x, A0); A1 = fmaf(V.z, w2.y, A1);      \
    A0 = fmaf(V.w, w3.x, A0); A1 = fmaf(V.w, w3.y, A1);

    for (int k4 = 0; k4 < C / 4; ++k4) {
        const float4 v0 = xp0[k4], v1 = xp1[k4], v2 = xp2[k4], v3 = xp3[k4];
        const float2 w0 = *reinterpret_cast<const float2*>(Wc + (4 * k4 + 0) * C);
        const float2 w1 = *reinterpret_cast<const float2*>(Wc + (4 * k4 + 1) * C);
        const float2 w2 = *reinterpret_cast<const float2*>(Wc + (4 * k4 + 2) * C);
        const float2 w3 = *reinterpret_cast<const float2*>(Wc + (4 * k4 + 3) * C);
        ROWFMA(v0, a00, a01)
        ROWFMA(v1, a10, a11)
        ROWFMA(v2, a20, a21)
        ROWFMA(v3, a30, a31)
    }
#undef ROWFMA

    const float2 asv = *reinterpret_cast<const float2*>(att_s + 2 * lane);
    const float2 adv = *reinterpret_cast<const float2*>(att_d + 2 * lane);
#define EPI(R, A0, A1) {                                                        \
    *reinterpret_cast<float2*>(&h[(size_t)(row0 + R) * C + 2 * lane]) =         \
        make_float2(A0, A1);                                                    \
    float ps = fmaf(A0, asv.x, A1 * asv.y);                                     \
    float pd = fmaf(A0, adv.x, A1 * adv.y);                                     \
    _Pragma("unroll")                                                           \
    for (int off = 32; off > 0; off >>= 1) {                                    \
        ps += __shfl_xor(ps, off); pd += __shfl_xor(pd, off);                   \
    }                                                                           \
    if (lane == 0) { asrc[row0 + R] = ps; adst[row0 + R] = pd; } }
    EPI(0, a00, a01)
    EPI(1, a10, a11)
    EPI(2, a20, a21)
    EPI(3, a30, a31)
#undef EPI
}

// Kernel 2: one wave per target edge i. Candidates = nlist[s_i] ++ nlist[d_i]
// (<= 64 with CAPN=32), one per lane. Dedup: j from the d-list counts only if
// j is NOT incident to s_i. Bitonic-sort candidates by edge id -> canonical,
// bit-deterministic summation order. Then softmax + h-row gather (lane = 2 ch).
__global__ __launch_bounds__(256) void gat_aggr(
    const int* __restrict__ packed, const float* __restrict__ h,
    const float* __restrict__ asrc, const float* __restrict__ adst,
    const float* __restrict__ bias,
    const int* __restrict__ cnt, const int* __restrict__ nlist,
    float* __restrict__ out)
{
    __shared__ float2 lst[4][64];
    const int tid = threadIdx.x, lane = tid & 63, wv = tid >> 6;
    const int i = blockIdx.x * 4 + wv;

    const u32 pi = (u32)packed[i];
    const u32 si = pi >> 16, di = pi & 0xffffu;
    const float adi = adst[i];
    int len_s = cnt[si]; if (len_s > CAPN) len_s = CAPN;
    int len_d = (di == si) ? 0 : cnt[di]; if (len_d > CAPN) len_d = CAPN;
    const int ntot = len_s + len_d;  // <= 64

    int key = 0x7fffffff, jg = 0;
    float sc = -INFINITY;
    bool valid = false;
    if (lane < ntot) {
        const bool from_s = lane < len_s;
        const int idx = from_s ? ((int)si * CAPN + lane)
                               : ((int)di * CAPN + (lane - len_s));
        const int j = nlist[idx];
        const u32 pj = (u32)packed[j];
        valid = from_s || ((pj >> 16) != si && (pj & 0xffffu) != si);
        if (valid) {
            const float s0 = adi + asrc[j];
            sc = s0 >= 0.f ? s0 : 0.2f * s0;
            key = j; jg = j;
        }
    }

    // row max + valid count (order-independent)
    float m = sc;
    #pragma unroll
    for (int off = 32; off > 0; off >>= 1) m = fmaxf(m, __shfl_xor(m, off));
    const int nvalid = (int)__popcll(__ballot(valid));

    // bitonic sort ascending by key (valid edge ids unique; invalid = INT_MAX ties)
    #pragma unroll
    for (int k = 2; k <= 64; k <<= 1) {
        #pragma unroll
        for (int st = k >> 1; st > 0; st >>= 1) {
            const int   ok = __shfl_xor(key, st);
            const int   oj = __shfl_xor(jg, st);
            const float os = __shfl_xor(sc, st);
            const bool takeMin = ((lane & k) == 0) == ((lane & st) == 0);
            const bool takeOther = takeMin ? (ok < key) : (ok > key);
            if (takeOther) { key = ok; jg = oj; sc = os; }
        }
    }
    lst[wv][lane] = make_float2(__int_as_float(jg), sc);

    // softmax weights + weighted sum of h rows (valid entries are lst[0..nvalid))
    float lsum = 0.f, o0 = 0.f, o1 = 0.f;
    for (int t = 0; t < nvalid; ++t) {
        const float2 e = lst[wv][t];
        const float p = __expf(e.y - m);
        const int j = __float_as_int(e.x);
        lsum += p;
        const float2 hv = *reinterpret_cast<const float2*>(&h[(size_t)j * C + 2 * lane]);
        o0 = fmaf(p, hv.x, o0);
        o1 = fmaf(p, hv.y, o1);
    }
    const float inv = 1.0f / lsum;
    const float2 bv = *reinterpret_cast<const float2*>(bias + 2 * lane);
    *reinterpret_cast<float2*>(&out[(size_t)i * C + 2 * lane]) =
        make_float2(fmaf(o0, inv, bv.x), fmaf(o1, inv, bv.y));
}

extern "C" void kernel_launch(void* const* d_in, const int* in_sizes, int n_in,
                              void* d_out, int out_size, void* d_ws, size_t ws_size,
                              hipStream_t stream) {
    const float* x     = (const float*)d_in[0];
    const int*   ei    = (const int*)d_in[1];
    const float* W     = (const float*)d_in[2];
    const float* att_s = (const float*)d_in[3];
    const float* att_d = (const float*)d_in[4];
    const float* bias  = (const float*)d_in[5];

    float* h      = (float*)d_ws;                 // E*C f32 = 4 MB
    float* asrc   = h + (size_t)E * C;            // 32 KB
    float* adst   = asrc + E;                     // 32 KB
    int*   packed = (int*)(adst + E);             // 32 KB
    int*   cnt    = packed + E;                   // 8 KB
    int*   nlist  = cnt + NNODE;                  // NNODE*CAPN*4 = 256 KB

    hipMemsetAsync(cnt, 0, NNODE * sizeof(int), stream);
    gat_prep<<<E / 16, 256, 0, stream>>>(x, W, att_s, att_d, ei,
                                         h, asrc, adst, packed, cnt, nlist);
    gat_aggr<<<E / 4, 256, 0, stream>>>(packed, h, asrc, adst, bias,
                                        cnt, nlist, (float*)d_out);
}